// Round 12
// baseline (83.884 us; speedup 1.0000x reference)
//
#include <hip/hip_runtime.h>
#include <hip/hip_bf16.h>

#define NG 8
#define NT 4096
#define DIN 1024
#define DOUT 4096
#define BM 128
#define BN 128
#define BK 64
#define KTILES (DIN / BK)   // 16
#define TILESZ (BM * BK * 2)        // one bf16 tile: 16KB
#define BUFSZ  (2 * TILESZ)         // A+B: 32KB per buffer
#define NTILES (DOUT / BN)          // 32 n-tiles
#define RTILES (NT / BM + NG)       // 40 row-tile slots

typedef __attribute__((ext_vector_type(4))) float f32x4;
typedef __attribute__((ext_vector_type(8))) short bf16x8;

// swizzled byte offset within a [rows][BK] bf16 LDS tile (row pitch 128B);
// XOR row&7 into the 16B-chunk bits -> conflict-free b128 frag reads (measured 0)
__device__ __forceinline__ int swz(int row, int colb) {
    return row * (BK * 2) + (colb ^ ((row & 7) << 4));
}

// 4 f32 -> 8B packed bf16 (compiler emits v_cvt_pk_bf16_f32 pairs)
__device__ __forceinline__ unsigned long long pack4bf(f32x4 v) {
    union { __hip_bfloat16 h; unsigned short u; } c0, c1, c2, c3;
    c0.h = __float2bfloat16(v[0]);
    c1.h = __float2bfloat16(v[1]);
    c2.h = __float2bfloat16(v[2]);
    c3.h = __float2bfloat16(v[3]);
    return (unsigned long long)c0.u | ((unsigned long long)c1.u << 16) |
           ((unsigned long long)c2.u << 32) | ((unsigned long long)c3.u << 48);
}

__global__ __launch_bounds__(256, 2)
void grouped_gemm_bf16(const float* __restrict__ x,
                       const int* __restrict__ offs,
                       const float* __restrict__ w,
                       float* __restrict__ out) {
    // double buffer, bf16: 2 x (A 16KB + B 16KB) = 64KB
    __shared__ char lds[2 * BUFSZ];

    // ---- 2D patch swizzle: consecutive blockIdx (round-robin over XCDs)
    //      cover an 8x8 patch (8 n-tiles x 8 row-tiles). Concurrent blocks on
    //      one XCD then share w-panel k-slices + x k-slices in its L2. ----
    const int lin = blockIdx.x;
    const int P   = lin >> 6;          // patch id (0..19)
    const int s   = lin & 63;          // position in patch
    const int pn  = s & 7,  pr = s >> 3;
    const int nt  = (P & 3) * 8 + pn;  // n-tile 0..31
    const int rt  = (P >> 2) * 8 + pr; // row-tile slot 0..39
    const int n0  = nt * BN;

    // ---- map rt -> (group, row0), group-aligned row tiles ----
    int row0 = 0, endg = 0, gsel = -1;
    {
        int acc = 0, prev = 0;
        for (int g = 0; g < NG; ++g) {
            int e = offs[g];
            int cnt = (e - prev + BM - 1) / BM;
            if (rt < acc + cnt) { gsel = g; row0 = prev + (rt - acc) * BM; endg = e; break; }
            acc += cnt; prev = e;
        }
    }
    if (gsel < 0) return;
    const float* wg = w + (size_t)gsel * DOUT * DIN;

    const int tid  = threadIdx.x;
    const int lane = tid & 63;
    const int wid  = tid >> 6;
    const int wr   = wid >> 1, wc = wid & 1;     // 2x2 wave grid
    const int lrow = lane & 15, kgrp = lane >> 4;
    const int sr   = tid >> 4;                   // staging row base (0..15)
    const int sc4  = tid & 15;                   // staging float4 col

    // staging source offsets (OOB A-rows clamped; outputs masked at C-store)
    int aoff[8], boff[8];
    #pragma unroll
    for (int i = 0; i < 8; ++i) {
        int r = sr + i * 16;
        int ar = row0 + r; if (ar >= endg) ar = endg - 1;
        aoff[i] = ar * DIN + sc4 * 4;
        boff[i] = (n0 + r) * DIN + sc4 * 4;
    }

    f32x4 acc[4][4];
    #pragma unroll
    for (int m = 0; m < 4; ++m)
        #pragma unroll
        for (int n = 0; n < 4; ++n)
            acc[m][n] = (f32x4){0.f, 0.f, 0.f, 0.f};

    f32x4 pA[8], pB[8];

    // ---- prologue: load + stage tile 0 into buf 0 ----
    #pragma unroll
    for (int i = 0; i < 8; ++i) pA[i] = *(const f32x4*)(x + aoff[i]);
    #pragma unroll
    for (int i = 0; i < 8; ++i) pB[i] = *(const f32x4*)(wg + boff[i]);
    {
        char* sA = lds;
        char* sB = lds + TILESZ;
        #pragma unroll
        for (int i = 0; i < 8; ++i)
            *(unsigned long long*)(sA + swz(sr + i * 16, sc4 * 8)) = pack4bf(pA[i]);
        #pragma unroll
        for (int i = 0; i < 8; ++i)
            *(unsigned long long*)(sB + swz(sr + i * 16, sc4 * 8)) = pack4bf(pB[i]);
    }
    asm volatile("s_waitcnt lgkmcnt(0)" ::: "memory");
    __builtin_amdgcn_sched_barrier(0);
    __builtin_amdgcn_s_barrier();
    __builtin_amdgcn_sched_barrier(0);

    for (int kt = 0; kt < KTILES; ++kt) {
        const int cur = kt & 1;
        char* lA = lds + cur * BUFSZ;
        char* lB = lA + TILESZ;

        // ---- issue next tile's 16 global loads to regs; NO vmcnt drain —
        //      compiler's counted vmcnt sits before the cvt (post-compute) ----
        if (kt + 1 < KTILES) {
            const int k0 = (kt + 1) * BK;
            #pragma unroll
            for (int i = 0; i < 8; ++i) pA[i] = *(const f32x4*)(x + aoff[i] + k0);
            #pragma unroll
            for (int i = 0; i < 8; ++i) pB[i] = *(const f32x4*)(wg + boff[i] + k0);
            __builtin_amdgcn_sched_barrier(0);
        }

        // ---- compute current tile from bf16 LDS buf[cur] ----
        __builtin_amdgcn_s_setprio(1);
        #pragma unroll
        for (int kk = 0; kk < 2; ++kk) {
            const int kb = kk * 64 + kgrp * 16;
            bf16x8 af[4], bb[4];
            #pragma unroll
            for (int m = 0; m < 4; ++m)
                af[m] = *(const bf16x8*)(lA + swz(wr * 64 + m * 16 + lrow, kb));
            #pragma unroll
            for (int n = 0; n < 4; ++n)
                bb[n] = *(const bf16x8*)(lB + swz(wc * 64 + n * 16 + lrow, kb));
            #pragma unroll
            for (int m = 0; m < 4; ++m)
                #pragma unroll
                for (int n = 0; n < 4; ++n)
                    acc[m][n] = __builtin_amdgcn_mfma_f32_16x16x32_bf16(
                        af[m], bb[n], acc[m][n], 0, 0, 0);
        }
        __builtin_amdgcn_s_setprio(0);

        // ---- cvt (counted vmcnt from reg deps) + ds_write into buf[cur^1],
        //      retire writes, then ONE raw barrier (no vmcnt drain) ----
        if (kt + 1 < KTILES) {
            char* sA = lds + (cur ^ 1) * BUFSZ;
            char* sB = sA + TILESZ;
            #pragma unroll
            for (int i = 0; i < 8; ++i)
                *(unsigned long long*)(sA + swz(sr + i * 16, sc4 * 8)) = pack4bf(pA[i]);
            #pragma unroll
            for (int i = 0; i < 8; ++i)
                *(unsigned long long*)(sB + swz(sr + i * 16, sc4 * 8)) = pack4bf(pB[i]);
            asm volatile("s_waitcnt lgkmcnt(0)" ::: "memory");
            __builtin_amdgcn_sched_barrier(0);
            __builtin_amdgcn_s_barrier();
            __builtin_amdgcn_sched_barrier(0);
        }
    }

    // ---- epilogue: C/D layout col=lane&15, row=(lane>>4)*4+j ----
    #pragma unroll
    for (int m = 0; m < 4; ++m) {
        #pragma unroll
        for (int j = 0; j < 4; ++j) {
            int row = row0 + wr * 64 + m * 16 + kgrp * 4 + j;
            if (row < endg) {
                #pragma unroll
                for (int n = 0; n < 4; ++n) {
                    int col = n0 + wc * 64 + n * 16 + lrow;
                    out[(size_t)row * DOUT + col] = acc[m][n][j];
                }
            }
        }
    }
}

extern "C" void kernel_launch(void* const* d_in, const int* in_sizes, int n_in,
                              void* d_out, int out_size, void* d_ws, size_t ws_size,
                              hipStream_t stream) {
    const float* x    = (const float*)d_in[0];
    const int*   offs = (const int*)d_in[1];
    const float* w    = (const float*)d_in[2];
    float* out = (float*)d_out;

    // 1D grid, patch-swizzled inside the kernel: 32 n-tiles x 40 row-slots
    grouped_gemm_bf16<<<dim3(NTILES * RTILES, 1, 1), 256, 0, stream>>>(x, offs, w, out);
}

// Round 13
// 81.506 us; speedup vs baseline: 1.0292x; 1.0292x over previous
//
#include <hip/hip_runtime.h>
#include <hip/hip_bf16.h>

#define NG 8
#define NT 4096
#define DIN 1024
#define DOUT 4096
#define BM 256
#define BN 128
#define BK 64
#define KTILES (DIN / BK)      // 16
#define NTILES (DOUT / BN)     // 32
#define RTILES (NT / BM + NG)  // 24 row-tile slots
#define ATILESZ (BM * BK * 2)  // A bf16 tile: 32KB
#define BTILESZ (BN * BK * 2)  // B bf16 tile: 16KB

typedef __attribute__((ext_vector_type(4))) float f32x4;
typedef __attribute__((ext_vector_type(8))) short bf16x8;

// async global->LDS, 16B/lane; dest = wave-uniform base + lane*16 (HW rule)
__device__ __forceinline__ void gld16(const void* g, void* l) {
    __builtin_amdgcn_global_load_lds(
        (const __attribute__((address_space(1))) void*)(g),
        (__attribute__((address_space(3))) void*)(l), 16, 0, 0);
}

// 4 f32 -> 8B packed bf16 (compiler emits v_cvt_pk_bf16_f32 pairs)
__device__ __forceinline__ unsigned long long pack4bf(f32x4 v) {
    union { __hip_bfloat16 h; unsigned short u; } c0, c1, c2, c3;
    c0.h = __float2bfloat16(v[0]);
    c1.h = __float2bfloat16(v[1]);
    c2.h = __float2bfloat16(v[2]);
    c3.h = __float2bfloat16(v[3]);
    return (unsigned long long)c0.u | ((unsigned long long)c1.u << 16) |
           ((unsigned long long)c2.u << 32) | ((unsigned long long)c3.u << 48);
}

// swizzled byte offset within a [rows][128B] bf16 tile (B tile, R10-proven)
__device__ __forceinline__ int swz(int row, int colb) {
    return row * 128 + (colb ^ ((row & 7) << 4));
}

// ---- pass 1: x f32 -> bf16 into workspace (25 MB HBM, ~4us) ----
__global__ __launch_bounds__(256)
void cvt_x_kernel(const float* __restrict__ x, short* __restrict__ xb) {
    const int n4 = NT * DIN / 4;
    for (int i = blockIdx.x * blockDim.x + threadIdx.x; i < n4;
         i += gridDim.x * blockDim.x) {
        f32x4 v = ((const f32x4*)x)[i];
        ((unsigned long long*)xb)[i] = pack4bf(v);
    }
}

__global__ __launch_bounds__(256, 2)
void grouped_gemm_bf16(const short* __restrict__ xb,
                       const int* __restrict__ offs,
                       const float* __restrict__ w,
                       float* __restrict__ out) {
    // A: double-buffered bf16 [2][256 rows][128B] = 64KB (global_load_lds dest)
    // B: single bf16 [128 rows][128B] = 16KB (reg-staged + cvt)
    __shared__ char lds[2 * ATILESZ + BTILESZ];
    char* ldsB = lds + 2 * ATILESZ;

    // ---- map blockIdx.y -> (group, row0), group-aligned 256-row tiles ----
    const int rt = blockIdx.y;
    const int n0 = blockIdx.x * BN;
    int row0 = 0, endg = 0, gsel = -1;
    {
        int acc = 0, prev = 0;
        for (int g = 0; g < NG; ++g) {
            int e = offs[g];
            int cnt = (e - prev + BM - 1) / BM;
            if (rt < acc + cnt) { gsel = g; row0 = prev + (rt - acc) * BM; endg = e; break; }
            acc += cnt; prev = e;
        }
    }
    if (gsel < 0) return;
    const float* wg = w + (size_t)gsel * DOUT * DIN;

    const int tid  = threadIdx.x;
    const int lane = tid & 63;
    const int wid  = tid >> 6;
    const int wrM  = wid >> 1, wcN = wid & 1;   // wave tile 128(M) x 64(N)
    const int lrow = lane & 15, kgrp = lane >> 4;

    // ---- A staging geometry (R4-proven): 32 stripes of 8 rows x 128B.
    //      wave wid covers stripe = i*4+wid; lane -> row r = stripe*8+(lane>>3),
    //      dest chunk = lane&7, SOURCE chunk = (lane&7)^(r&7) (inverse swizzle;
    //      frag read applies the same XOR). ----
    int axoff[8], sbaseA[8];
    #pragma unroll
    for (int i = 0; i < 8; ++i) {
        int stripe = i * 4 + wid;
        int r = stripe * 8 + (lane >> 3);
        int cs = (lane & 7) ^ (r & 7);
        int ar = row0 + r; if (ar >= endg) ar = endg - 1;   // clamp; masked at store
        axoff[i]  = ar * DIN + cs * 8;      // short units (8 shorts = 16B)
        sbaseA[i] = stripe * 1024;          // bytes (wave-uniform)
    }
    // ---- B staging: thread covers rows sr+i*16 (0..127), f32x4 col sc4 ----
    const int sr = tid >> 4, sc4 = tid & 15;
    int boff[8];
    #pragma unroll
    for (int i = 0; i < 8; ++i) boff[i] = (n0 + sr + i * 16) * DIN + sc4 * 4;

    f32x4 acc[8][4];
    #pragma unroll
    for (int m = 0; m < 8; ++m)
        #pragma unroll
        for (int n = 0; n < 4; ++n)
            acc[m][n] = (f32x4){0.f, 0.f, 0.f, 0.f};

    f32x4 pB[8];

    // ---- prologue: stage tile 0 (A via DMA, B via reg+cvt) ----
    #pragma unroll
    for (int i = 0; i < 8; ++i) gld16(xb + axoff[i], lds + sbaseA[i]);
    #pragma unroll
    for (int i = 0; i < 8; ++i) pB[i] = *(const f32x4*)(wg + boff[i]);
    #pragma unroll
    for (int i = 0; i < 8; ++i)
        *(unsigned long long*)(ldsB + swz(sr + i * 16, sc4 * 8)) = pack4bf(pB[i]);
    asm volatile("s_waitcnt vmcnt(0) lgkmcnt(0)" ::: "memory");
    __builtin_amdgcn_sched_barrier(0);
    __builtin_amdgcn_s_barrier();
    __builtin_amdgcn_sched_barrier(0);

    for (int kt = 0; kt < KTILES; ++kt) {
        const int cur = kt & 1;
        const char* lA = lds + cur * ATILESZ;

        // ---- issue next tile's loads: B->regs, A->DMA into bufA[cur^1]
        //      (bufA[cur^1] readers finished before the last barrier) ----
        if (kt + 1 < KTILES) {
            const int k0 = (kt + 1) * BK;
            #pragma unroll
            for (int i = 0; i < 8; ++i) pB[i] = *(const f32x4*)(wg + boff[i] + k0);
            #pragma unroll
            for (int i = 0; i < 8; ++i)
                gld16(xb + axoff[i] + k0, lds + (cur ^ 1) * ATILESZ + sbaseA[i]);
            __builtin_amdgcn_sched_barrier(0);
        }

        // ---- compute: wave tile 128x64, 64 MFMA/step ----
        __builtin_amdgcn_s_setprio(1);
        #pragma unroll
        for (int kk = 0; kk < 2; ++kk) {
            const int kb = kk * 64 + kgrp * 16;   // byte col within 128B row
            bf16x8 af[8], bb[4];
            #pragma unroll
            for (int m = 0; m < 8; ++m) {
                int r = wrM * 128 + m * 16 + lrow;
                af[m] = *(const bf16x8*)(lA + r * 128 + (((kb >> 4) ^ (r & 7)) << 4));
            }
            #pragma unroll
            for (int n = 0; n < 4; ++n)
                bb[n] = *(const bf16x8*)(ldsB + swz(wcN * 64 + n * 16 + lrow, kb));
            #pragma unroll
            for (int m = 0; m < 8; ++m)
                #pragma unroll
                for (int n = 0; n < 4; ++n)
                    acc[m][n] = __builtin_amdgcn_mfma_f32_16x16x32_bf16(
                        af[m], bb[n], acc[m][n], 0, 0, 0);
        }
        __builtin_amdgcn_s_setprio(0);

        if (kt + 1 < KTILES) {
            // barrier 2: all waves done READING ldsB (raw, no drain)
            __builtin_amdgcn_sched_barrier(0);
            __builtin_amdgcn_s_barrier();
            __builtin_amdgcn_sched_barrier(0);

            // cvt (compiler-counted vmcnt on pB) + ds_write B
            #pragma unroll
            for (int i = 0; i < 8; ++i)
                *(unsigned long long*)(ldsB + swz(sr + i * 16, sc4 * 8)) = pack4bf(pB[i]);

            // barrier 1: B writes retired AND A-DMA complete, then visible
            asm volatile("s_waitcnt vmcnt(0) lgkmcnt(0)" ::: "memory");
            __builtin_amdgcn_sched_barrier(0);
            __builtin_amdgcn_s_barrier();
            __builtin_amdgcn_sched_barrier(0);
        }
    }

    // ---- epilogue: C/D layout col=lane&15, row=(lane>>4)*4+j ----
    #pragma unroll
    for (int m = 0; m < 8; ++m) {
        #pragma unroll
        for (int j = 0; j < 4; ++j) {
            int row = row0 + wrM * 128 + m * 16 + kgrp * 4 + j;
            if (row < endg) {
                #pragma unroll
                for (int n = 0; n < 4; ++n) {
                    int col = n0 + wcN * 64 + n * 16 + lrow;
                    out[(size_t)row * DOUT + col] = acc[m][n][j];
                }
            }
        }
    }
}

extern "C" void kernel_launch(void* const* d_in, const int* in_sizes, int n_in,
                              void* d_out, int out_size, void* d_ws, size_t ws_size,
                              hipStream_t stream) {
    const float* x    = (const float*)d_in[0];
    const int*   offs = (const int*)d_in[1];
    const float* w    = (const float*)d_in[2];
    float* out = (float*)d_out;
    short* xb  = (short*)d_ws;   // NT*DIN bf16 = 8.4 MB

    cvt_x_kernel<<<1024, 256, 0, stream>>>(x, xb);
    dim3 grid(NTILES, RTILES, 1);
    grouped_gemm_bf16<<<grid, 256, 0, stream>>>(xb, offs, w, out);
}